// Round 8
// baseline (216.331 us; speedup 1.0000x reference)
//
#include <hip/hip_runtime.h>
#include <hip/hip_bf16.h>
#include <math.h>

#define S 256
#define D 128
#define H 4
#define HD 32
#define NT (S * S)

constexpr float EPS = 1e-5f;
constexpr float EXPC = 0.17677669529663687f * 1.44269504088896f;  // scale*log2(e)

typedef short bf16x8 __attribute__((ext_vector_type(8)));
typedef float floatx4 __attribute__((ext_vector_type(4)));

union BfBits { __hip_bfloat16 b; unsigned short u; };
__device__ inline unsigned short f2bf_bits(float f) {
  BfBits t;
  t.b = __float2bfloat16(f);
  return t.u;
}
__device__ inline short f2bf_s(float f) { return (short)f2bf_bits(f); }
__device__ inline float bfbits2f(unsigned short u) {
  union { float f; unsigned int i; } t;
  t.i = ((unsigned int)u) << 16;
  return t.f;
}
// split x into bf16 hi + bf16 lo with x ~= hi + lo (error <= 2^-18 relative)
__device__ inline void split_bf(float x, unsigned short& hi, unsigned short& lo) {
  hi = f2bf_bits(x);
  lo = f2bf_bits(x - bfbits2f(hi));
}

// ---------------------------------------------------------------------------
// K0: split the four 128x128 fp32 weights into bf16 hi/lo pairs, original
// [d][c] layout (== MFMA A-operand row layout). Order: q, k, v, o.
// ---------------------------------------------------------------------------
__global__ __launch_bounds__(256) void wsplit_kernel(
    const float* __restrict__ wq, const float* __restrict__ wk,
    const float* __restrict__ wv, const float* __restrict__ wo,
    unsigned short* __restrict__ whi, unsigned short* __restrict__ wlo) {
  int idx = blockIdx.x * 256 + threadIdx.x;  // 0..16383
  const float* srcs[4] = {wq, wk, wv, wo};
#pragma unroll
  for (int m = 0; m < 4; m++) {
    unsigned short hi, lo;
    split_bf(srcs[m][idx], hi, lo);
    whi[m * 16384 + idx] = hi;
    wlo[m * 16384 + idx] = lo;
  }
}

// ---------------------------------------------------------------------------
// K1: fused LayerNorm + QKV projection via bf16 MFMA (R4 structure, 49 µs).
// launch_bounds(256,8): VGPR 44 fits the 64-reg cap, LDS 17.4 KB x 8 = 139 KB
// -> up to 8 blocks/CU for latency hiding (was 4).
// ---------------------------------------------------------------------------
#define XPAD 8
__global__ __launch_bounds__(256, 8) void qkv_ln_mfma_kernel(
    const float* __restrict__ pair, const float* __restrict__ ln_w,
    const unsigned short* __restrict__ Whi,
    const unsigned short* __restrict__ Wlo, unsigned short* __restrict__ Qb,
    unsigned short* __restrict__ Kb, unsigned short* __restrict__ Vt) {
  __shared__ unsigned short xhi[64][D + XPAD];  // 17.4 KB
  const int t0 = blockIdx.x * 64;
  const int wave = threadIdx.x >> 6;
  const int lane = threadIdx.x & 63;

  // ---- LayerNorm: each wave normalizes 16 tokens (2 elems/lane) ----
  {
    float2 w2 = *(const float2*)(ln_w + lane * 2);
    for (int tt = 0; tt < 16; tt++) {
      int tok = wave * 16 + tt;
      float2 x = *(const float2*)(pair + (size_t)(t0 + tok) * D + lane * 2);
      float s = x.x + x.y;
#pragma unroll
      for (int o = 32; o > 0; o >>= 1) s += __shfl_xor(s, o);
      float mu = s * (1.0f / D);
      float a = x.x - mu;
      float b = x.y - mu;
      float vs = a * a + b * b;
#pragma unroll
      for (int o = 32; o > 0; o >>= 1) vs += __shfl_xor(vs, o);
      float r = rsqrtf(vs * (1.0f / D) + EPS);
      unsigned int h0 = f2bf_bits(a * r * w2.x);
      unsigned int h1 = f2bf_bits(b * r * w2.y);
      *(unsigned int*)&xhi[tok][lane * 2] = h0 | (h1 << 16);
    }
  }
  __syncthreads();

  const int c16 = lane & 15;
  const int quad = lane >> 4;
  const int i_ = t0 >> 8;      // pair row index
  const int jbase = t0 & 255;  // token offset within the pair row

  // ---- 3 passes: mat 0=Q, 1=K, 2=V; wave owns m-tiles wave*2, wave*2+1 ----
  for (int mat = 0; mat < 3; mat++) {
    floatx4 acc[2][4];
#pragma unroll
    for (int mi = 0; mi < 2; mi++)
#pragma unroll
      for (int nt = 0; nt < 4; nt++) acc[mi][nt] = (floatx4){0.f, 0.f, 0.f, 0.f};

    for (int ks = 0; ks < 4; ks++) {
      const int k0 = ks * 32;
      bf16x8 bh[4];
#pragma unroll
      for (int nt = 0; nt < 4; nt++)
        bh[nt] = *(const bf16x8*)&xhi[nt * 16 + c16][k0 + quad * 8];
#pragma unroll
      for (int mi = 0; mi < 2; mi++) {
        const int m0 = (wave * 2 + mi) * 16;
        bf16x8 ah = *(const bf16x8*)(Whi + mat * 16384 + (m0 + c16) * D + k0 + quad * 8);
        bf16x8 al = *(const bf16x8*)(Wlo + mat * 16384 + (m0 + c16) * D + k0 + quad * 8);
#pragma unroll
        for (int nt = 0; nt < 4; nt++) {
          acc[mi][nt] = __builtin_amdgcn_mfma_f32_16x16x32_bf16(ah, bh[nt], acc[mi][nt], 0, 0, 0);
          acc[mi][nt] = __builtin_amdgcn_mfma_f32_16x16x32_bf16(al, bh[nt], acc[mi][nt], 0, 0, 0);
        }
      }
    }

    // ---- epilogue for this matrix ----
#pragma unroll
    for (int mi = 0; mi < 2; mi++) {
      const int m0 = (wave * 2 + mi) * 16;
      const int d0 = m0 + quad * 4;  // 4 consecutive out dims
      const int h = d0 >> 5;
      const int hd = d0 & 31;
#pragma unroll
      for (int nt = 0; nt < 4; nt++) {
        const int j = jbase + nt * 16 + c16;
        floatx4 v4 = acc[mi][nt];
        if (mat < 2) {
          ushort4 pk;
          pk.x = f2bf_bits(v4[0]);
          pk.y = f2bf_bits(v4[1]);
          pk.z = f2bf_bits(v4[2]);
          pk.w = f2bf_bits(v4[3]);
          unsigned short* dst = (mat == 0) ? Qb : Kb;
          size_t off = (((size_t)h * S + i_) * S + j) * HD + hd;
          *(ushort4*)(dst + off) = pk;
        } else {
#pragma unroll
          for (int r = 0; r < 4; r++) {
            size_t off = (((size_t)h * S + i_) * HD + (hd + r)) * S + j;
            Vt[off] = f2bf_bits(v4[r]);
          }
        }
      }
    }
  }
}

// ---------------------------------------------------------------------------
// K2: FUSED flash attention + output projection, regridded for occupancy.
// Block = (pair-row i, quarter p): 256 threads = 4 waves = 4 heads; each wave
// runs attention for its head over the quarter's 64 queries, deposits O as
// packed (hi | lo<<16) bf16 into LDS, then all 4 waves project those 64
// tokens (wave owns 2 outdim tiles). 1024 blocks, 34 KB LDS -> 4 blocks/CU
// (16 waves/CU) vs R6's 1 block/CU. Each token row of `out` is written
// entirely by one block -> full-cache-line writes.
// ---------------------------------------------------------------------------
#define OLD 133  // LDS row stride (words) for O buffer
__global__ __launch_bounds__(256, 4) void attn_oproj_kernel(
    const unsigned short* __restrict__ Qb, const unsigned short* __restrict__ Kb,
    const unsigned short* __restrict__ Vt, const unsigned short* __restrict__ Whi,
    const unsigned short* __restrict__ Wlo, float* __restrict__ out) {
  __shared__ unsigned int Ols[64][OLD];  // 34 KB
  const int i = blockIdx.x;
  const int p = blockIdx.y;  // quarter: tokens p*64 .. p*64+63
  const int h = threadIdx.x >> 6;  // wave = head
  const int lane = threadIdx.x & 63;
  const int c = lane & 15;
  const int quad = lane >> 4;
  const int q0 = p * 64;

  const unsigned short* Qbase = Qb + (((size_t)h * S + i) * S) * HD;
  const unsigned short* Kbase = Kb + (((size_t)h * S + i) * S) * HD;
  const unsigned short* Vbase = Vt + (((size_t)h * S + i) * HD) * S;

  // ---- Phase 1: attention for this head's 64 queries (4 q-tiles) ----
  bf16x8 qf[4];
#pragma unroll
  for (int qt = 0; qt < 4; qt++)
    qf[qt] = *(const bf16x8*)(Qbase + (size_t)(q0 + qt * 16 + c) * HD + quad * 8);

  floatx4 acc[2][4];
#pragma unroll
  for (int dt = 0; dt < 2; dt++)
#pragma unroll
    for (int qt = 0; qt < 4; qt++) acc[dt][qt] = (floatx4){0.f, 0.f, 0.f, 0.f};
  float lsum[4] = {0.f, 0.f, 0.f, 0.f};

  const int permc = ((c >> 2) * 8) + (c & 3);

  for (int jb = 0; jb < S; jb += 32) {
    bf16x8 kf0 = *(const bf16x8*)(Kbase + (size_t)(jb + permc + 0) * HD + quad * 8);
    bf16x8 kf1 = *(const bf16x8*)(Kbase + (size_t)(jb + permc + 4) * HD + quad * 8);
    bf16x8 vf0 = *(const bf16x8*)(Vbase + (size_t)(0 * 16 + c) * S + jb + quad * 8);
    bf16x8 vf1 = *(const bf16x8*)(Vbase + (size_t)(1 * 16 + c) * S + jb + quad * 8);

#pragma unroll
    for (int qt = 0; qt < 4; qt++) {
      floatx4 s0 = __builtin_amdgcn_mfma_f32_16x16x32_bf16(
          kf0, qf[qt], (floatx4){0.f, 0.f, 0.f, 0.f}, 0, 0, 0);
      floatx4 s1 = __builtin_amdgcn_mfma_f32_16x16x32_bf16(
          kf1, qf[qt], (floatx4){0.f, 0.f, 0.f, 0.f}, 0, 0, 0);
      float pr[8];
#pragma unroll
      for (int r = 0; r < 4; r++) pr[r] = exp2f(s0[r] * EXPC);
#pragma unroll
      for (int r = 0; r < 4; r++) pr[4 + r] = exp2f(s1[r] * EXPC);
      float ls = 0.f;
#pragma unroll
      for (int r = 0; r < 8; r++) ls += pr[r];
      lsum[qt] += ls;
      bf16x8 pf;
#pragma unroll
      for (int r = 0; r < 8; r++) pf[r] = f2bf_s(pr[r]);
      acc[0][qt] = __builtin_amdgcn_mfma_f32_16x16x32_bf16(vf0, pf, acc[0][qt], 0, 0, 0);
      acc[1][qt] = __builtin_amdgcn_mfma_f32_16x16x32_bf16(vf1, pf, acc[1][qt], 0, 0, 0);
    }
  }

#pragma unroll
  for (int qt = 0; qt < 4; qt++) {
    float l = lsum[qt];
    l += __shfl_xor(l, 16);
    l += __shfl_xor(l, 32);
    lsum[qt] = 1.0f / l;
  }

  // ---- deposit O (head's 32 dims) for the 64 tokens as packed hi|lo<<16 ----
#pragma unroll
  for (int t = 0; t < 4; t++) {
    const float inv = lsum[t];
#pragma unroll
    for (int dt = 0; dt < 2; dt++) {
      floatx4 v4 = acc[dt][t];
      uint4 st;
      unsigned short hh, ll;
      split_bf(v4[0] * inv, hh, ll); st.x = (unsigned)hh | ((unsigned)ll << 16);
      split_bf(v4[1] * inv, hh, ll); st.y = (unsigned)hh | ((unsigned)ll << 16);
      split_bf(v4[2] * inv, hh, ll); st.z = (unsigned)hh | ((unsigned)ll << 16);
      split_bf(v4[3] * inv, hh, ll); st.w = (unsigned)hh | ((unsigned)ll << 16);
      *(uint4*)&Ols[t * 16 + c][h * 32 + dt * 16 + quad * 4] = st;
    }
  }

  // ---- load wo fragments: wave owns outdim tiles wave*32, wave*32+16 ----
  bf16x8 woh[2][4], wol[2][4];
#pragma unroll
  for (int mi = 0; mi < 2; mi++)
#pragma unroll
    for (int ks = 0; ks < 4; ks++) {
      const int m0 = h * 32 + mi * 16;
      woh[mi][ks] = *(const bf16x8*)(Whi + 3 * 16384 + (m0 + c) * D + ks * 32 + quad * 8);
      wol[mi][ks] = *(const bf16x8*)(Wlo + 3 * 16384 + (m0 + c) * D + ks * 32 + quad * 8);
    }

  __syncthreads();

  // ---- Phase 2: project the 64 tokens: out = O @ wo^T ----
  floatx4 oacc[2][4];
#pragma unroll
  for (int mi = 0; mi < 2; mi++)
#pragma unroll
    for (int nt = 0; nt < 4; nt++) oacc[mi][nt] = (floatx4){0.f, 0.f, 0.f, 0.f};

#pragma unroll
  for (int ks = 0; ks < 4; ks++) {
#pragma unroll
    for (int nt = 0; nt < 4; nt++) {
      const unsigned int* src = &Ols[nt * 16 + c][ks * 32 + quad * 8];
      uint4 u0 = *(const uint4*)(src);
      uint4 u1 = *(const uint4*)(src + 4);
      unsigned int bhw[4], blw[4];
      bhw[0] = (u0.x & 0xFFFFu) | (u0.y << 16);
      blw[0] = (u0.x >> 16) | (u0.y & 0xFFFF0000u);
      bhw[1] = (u0.z & 0xFFFFu) | (u0.w << 16);
      blw[1] = (u0.z >> 16) | (u0.w & 0xFFFF0000u);
      bhw[2] = (u1.x & 0xFFFFu) | (u1.y << 16);
      blw[2] = (u1.x >> 16) | (u1.y & 0xFFFF0000u);
      bhw[3] = (u1.z & 0xFFFFu) | (u1.w << 16);
      blw[3] = (u1.z >> 16) | (u1.w & 0xFFFF0000u);
      bf16x8 bh = *(bf16x8*)bhw;
      bf16x8 bl = *(bf16x8*)blw;
#pragma unroll
      for (int mi = 0; mi < 2; mi++) {
        oacc[mi][nt] = __builtin_amdgcn_mfma_f32_16x16x32_bf16(woh[mi][ks], bh, oacc[mi][nt], 0, 0, 0);
        oacc[mi][nt] = __builtin_amdgcn_mfma_f32_16x16x32_bf16(woh[mi][ks], bl, oacc[mi][nt], 0, 0, 0);
        oacc[mi][nt] = __builtin_amdgcn_mfma_f32_16x16x32_bf16(wol[mi][ks], bh, oacc[mi][nt], 0, 0, 0);
      }
    }
  }

#pragma unroll
  for (int mi = 0; mi < 2; mi++) {
    const int m0 = h * 32 + mi * 16;
#pragma unroll
    for (int nt = 0; nt < 4; nt++) {
      float4 st;
      st.x = oacc[mi][nt][0];
      st.y = oacc[mi][nt][1];
      st.z = oacc[mi][nt][2];
      st.w = oacc[mi][nt][3];
      *(float4*)(out + ((size_t)i * S + q0 + nt * 16 + c) * D + m0 + quad * 4) = st;
    }
  }
}

// ---------------------------------------------------------------------------
extern "C" void kernel_launch(void* const* d_in, const int* in_sizes, int n_in,
                              void* d_out, int out_size, void* d_ws,
                              size_t ws_size, hipStream_t stream) {
  const float* pair = (const float*)d_in[0];
  const float* ln_w = (const float*)d_in[1];
  const float* wq = (const float*)d_in[2];
  const float* wk = (const float*)d_in[3];
  const float* wv = (const float*)d_in[4];
  const float* wo = (const float*)d_in[5];
  float* out = (float*)d_out;

  const size_t NE = (size_t)NT * D;  // 8388608
  unsigned short* base = (unsigned short*)d_ws;
  unsigned short* Qb = base;
  unsigned short* Kb = base + NE;
  unsigned short* Vt = base + 2 * NE;
  unsigned short* Whi = base + 3 * NE;
  unsigned short* Wlo = base + 3 * NE + 4 * 16384;

  wsplit_kernel<<<64, 256, 0, stream>>>(wq, wk, wv, wo, Whi, Wlo);
  qkv_ln_mfma_kernel<<<NT / 64, 256, 0, stream>>>(pair, ln_w, Whi, Wlo, Qb, Kb,
                                                  Vt);
  attn_oproj_kernel<<<dim3(S, 4), 256, 0, stream>>>(Qb, Kb, Vt, Whi, Wlo, out);
}

// Round 9
// 163.336 us; speedup vs baseline: 1.3244x; 1.3244x over previous
//
#include <hip/hip_runtime.h>
#include <hip/hip_bf16.h>
#include <math.h>

#define S 256
#define D 128
#define H 4
#define HD 32
#define NT (S * S)

constexpr float EPS = 1e-5f;
constexpr float EXPC = 0.17677669529663687f * 1.44269504088896f;  // scale*log2(e)

typedef short bf16x8 __attribute__((ext_vector_type(8)));
typedef float floatx4 __attribute__((ext_vector_type(4)));

union BfBits { __hip_bfloat16 b; unsigned short u; };
__device__ inline unsigned short f2bf_bits(float f) {
  BfBits t;
  t.b = __float2bfloat16(f);
  return t.u;
}
__device__ inline short f2bf_s(float f) { return (short)f2bf_bits(f); }
__device__ inline float bfbits2f(unsigned short u) {
  union { float f; unsigned int i; } t;
  t.i = ((unsigned int)u) << 16;
  return t.f;
}
// split x into bf16 hi + bf16 lo with x ~= hi + lo (error <= 2^-18 relative)
__device__ inline void split_bf(float x, unsigned short& hi, unsigned short& lo) {
  hi = f2bf_bits(x);
  lo = f2bf_bits(x - bfbits2f(hi));
}

// ---------------------------------------------------------------------------
// K0: split the four 128x128 fp32 weights into bf16 hi/lo pairs, original
// [d][c] layout (== MFMA A-operand row layout). Order: q, k, v, o.
// ---------------------------------------------------------------------------
__global__ __launch_bounds__(256) void wsplit_kernel(
    const float* __restrict__ wq, const float* __restrict__ wk,
    const float* __restrict__ wv, const float* __restrict__ wo,
    unsigned short* __restrict__ whi, unsigned short* __restrict__ wlo) {
  int idx = blockIdx.x * 256 + threadIdx.x;  // 0..16383
  const float* srcs[4] = {wq, wk, wv, wo};
#pragma unroll
  for (int m = 0; m < 4; m++) {
    unsigned short hi, lo;
    split_bf(srcs[m][idx], hi, lo);
    whi[m * 16384 + idx] = hi;
    wlo[m * 16384 + idx] = lo;
  }
}

// ---------------------------------------------------------------------------
// K1: fused LayerNorm + QKV projection via bf16 MFMA.
// __launch_bounds__(256,4): the (256,8) experiment forced a 64-VGPR cap ->
// compiler spilled to scratch (FETCH 17->79 MB, WRITE 49->190 MB, 2x slower).
// VGPR 44 @ (256,4), no spill; grid 1024 = 4 blocks/CU is the TLP limit.
// ks loop unroll-2 pipelines next iteration's LDS/weight loads behind MFMAs.
// ---------------------------------------------------------------------------
#define XPAD 8
__global__ __launch_bounds__(256, 4) void qkv_ln_mfma_kernel(
    const float* __restrict__ pair, const float* __restrict__ ln_w,
    const unsigned short* __restrict__ Whi,
    const unsigned short* __restrict__ Wlo, unsigned short* __restrict__ Qb,
    unsigned short* __restrict__ Kb, unsigned short* __restrict__ Vt) {
  __shared__ unsigned short xhi[64][D + XPAD];  // 17.4 KB
  const int t0 = blockIdx.x * 64;
  const int wave = threadIdx.x >> 6;
  const int lane = threadIdx.x & 63;

  // ---- LayerNorm: each wave normalizes 16 tokens (2 elems/lane) ----
  {
    float2 w2 = *(const float2*)(ln_w + lane * 2);
    for (int tt = 0; tt < 16; tt++) {
      int tok = wave * 16 + tt;
      float2 x = *(const float2*)(pair + (size_t)(t0 + tok) * D + lane * 2);
      float s = x.x + x.y;
#pragma unroll
      for (int o = 32; o > 0; o >>= 1) s += __shfl_xor(s, o);
      float mu = s * (1.0f / D);
      float a = x.x - mu;
      float b = x.y - mu;
      float vs = a * a + b * b;
#pragma unroll
      for (int o = 32; o > 0; o >>= 1) vs += __shfl_xor(vs, o);
      float r = rsqrtf(vs * (1.0f / D) + EPS);
      unsigned int h0 = f2bf_bits(a * r * w2.x);
      unsigned int h1 = f2bf_bits(b * r * w2.y);
      *(unsigned int*)&xhi[tok][lane * 2] = h0 | (h1 << 16);
    }
  }
  __syncthreads();

  const int c16 = lane & 15;
  const int quad = lane >> 4;
  const int i_ = t0 >> 8;      // pair row index
  const int jbase = t0 & 255;  // token offset within the pair row

  // ---- 3 passes: mat 0=Q, 1=K, 2=V; wave owns m-tiles wave*2, wave*2+1 ----
  for (int mat = 0; mat < 3; mat++) {
    floatx4 acc[2][4];
#pragma unroll
    for (int mi = 0; mi < 2; mi++)
#pragma unroll
      for (int nt = 0; nt < 4; nt++) acc[mi][nt] = (floatx4){0.f, 0.f, 0.f, 0.f};

#pragma unroll 2
    for (int ks = 0; ks < 4; ks++) {
      const int k0 = ks * 32;
      bf16x8 bh[4];
#pragma unroll
      for (int nt = 0; nt < 4; nt++)
        bh[nt] = *(const bf16x8*)&xhi[nt * 16 + c16][k0 + quad * 8];
#pragma unroll
      for (int mi = 0; mi < 2; mi++) {
        const int m0 = (wave * 2 + mi) * 16;
        bf16x8 ah = *(const bf16x8*)(Whi + mat * 16384 + (m0 + c16) * D + k0 + quad * 8);
        bf16x8 al = *(const bf16x8*)(Wlo + mat * 16384 + (m0 + c16) * D + k0 + quad * 8);
#pragma unroll
        for (int nt = 0; nt < 4; nt++) {
          acc[mi][nt] = __builtin_amdgcn_mfma_f32_16x16x32_bf16(ah, bh[nt], acc[mi][nt], 0, 0, 0);
          acc[mi][nt] = __builtin_amdgcn_mfma_f32_16x16x32_bf16(al, bh[nt], acc[mi][nt], 0, 0, 0);
        }
      }
    }

    // ---- epilogue for this matrix ----
#pragma unroll
    for (int mi = 0; mi < 2; mi++) {
      const int m0 = (wave * 2 + mi) * 16;
      const int d0 = m0 + quad * 4;  // 4 consecutive out dims
      const int h = d0 >> 5;
      const int hd = d0 & 31;
#pragma unroll
      for (int nt = 0; nt < 4; nt++) {
        const int j = jbase + nt * 16 + c16;
        floatx4 v4 = acc[mi][nt];
        if (mat < 2) {
          ushort4 pk;
          pk.x = f2bf_bits(v4[0]);
          pk.y = f2bf_bits(v4[1]);
          pk.z = f2bf_bits(v4[2]);
          pk.w = f2bf_bits(v4[3]);
          unsigned short* dst = (mat == 0) ? Qb : Kb;
          size_t off = (((size_t)h * S + i_) * S + j) * HD + hd;
          *(ushort4*)(dst + off) = pk;
        } else {
#pragma unroll
          for (int r = 0; r < 4; r++) {
            size_t off = (((size_t)h * S + i_) * HD + (hd + r)) * S + j;
            Vt[off] = f2bf_bits(v4[r]);
          }
        }
      }
    }
  }
}

// ---------------------------------------------------------------------------
// K2: FUSED flash attention + output projection (R7 regrid — kept).
// Block = (pair-row i, quarter p): 256 threads = 4 waves = 4 heads; each wave
// runs attention for its head over the quarter's 64 queries, deposits O as
// packed (hi | lo<<16) bf16 into LDS, then all 4 waves project those 64
// tokens (wave owns 2 outdim tiles). 1024 blocks, 34 KB LDS -> 4 blocks/CU.
// ---------------------------------------------------------------------------
#define OLD 133  // LDS row stride (words) for O buffer
__global__ __launch_bounds__(256, 4) void attn_oproj_kernel(
    const unsigned short* __restrict__ Qb, const unsigned short* __restrict__ Kb,
    const unsigned short* __restrict__ Vt, const unsigned short* __restrict__ Whi,
    const unsigned short* __restrict__ Wlo, float* __restrict__ out) {
  __shared__ unsigned int Ols[64][OLD];  // 34 KB
  const int i = blockIdx.x;
  const int p = blockIdx.y;  // quarter: tokens p*64 .. p*64+63
  const int h = threadIdx.x >> 6;  // wave = head
  const int lane = threadIdx.x & 63;
  const int c = lane & 15;
  const int quad = lane >> 4;
  const int q0 = p * 64;

  const unsigned short* Qbase = Qb + (((size_t)h * S + i) * S) * HD;
  const unsigned short* Kbase = Kb + (((size_t)h * S + i) * S) * HD;
  const unsigned short* Vbase = Vt + (((size_t)h * S + i) * HD) * S;

  // ---- Phase 1: attention for this head's 64 queries (4 q-tiles) ----
  bf16x8 qf[4];
#pragma unroll
  for (int qt = 0; qt < 4; qt++)
    qf[qt] = *(const bf16x8*)(Qbase + (size_t)(q0 + qt * 16 + c) * HD + quad * 8);

  floatx4 acc[2][4];
#pragma unroll
  for (int dt = 0; dt < 2; dt++)
#pragma unroll
    for (int qt = 0; qt < 4; qt++) acc[dt][qt] = (floatx4){0.f, 0.f, 0.f, 0.f};
  float lsum[4] = {0.f, 0.f, 0.f, 0.f};

  const int permc = ((c >> 2) * 8) + (c & 3);

  for (int jb = 0; jb < S; jb += 32) {
    bf16x8 kf0 = *(const bf16x8*)(Kbase + (size_t)(jb + permc + 0) * HD + quad * 8);
    bf16x8 kf1 = *(const bf16x8*)(Kbase + (size_t)(jb + permc + 4) * HD + quad * 8);
    bf16x8 vf0 = *(const bf16x8*)(Vbase + (size_t)(0 * 16 + c) * S + jb + quad * 8);
    bf16x8 vf1 = *(const bf16x8*)(Vbase + (size_t)(1 * 16 + c) * S + jb + quad * 8);

#pragma unroll
    for (int qt = 0; qt < 4; qt++) {
      floatx4 s0 = __builtin_amdgcn_mfma_f32_16x16x32_bf16(
          kf0, qf[qt], (floatx4){0.f, 0.f, 0.f, 0.f}, 0, 0, 0);
      floatx4 s1 = __builtin_amdgcn_mfma_f32_16x16x32_bf16(
          kf1, qf[qt], (floatx4){0.f, 0.f, 0.f, 0.f}, 0, 0, 0);
      float pr[8];
#pragma unroll
      for (int r = 0; r < 4; r++) pr[r] = exp2f(s0[r] * EXPC);
#pragma unroll
      for (int r = 0; r < 4; r++) pr[4 + r] = exp2f(s1[r] * EXPC);
      float ls = 0.f;
#pragma unroll
      for (int r = 0; r < 8; r++) ls += pr[r];
      lsum[qt] += ls;
      bf16x8 pf;
#pragma unroll
      for (int r = 0; r < 8; r++) pf[r] = f2bf_s(pr[r]);
      acc[0][qt] = __builtin_amdgcn_mfma_f32_16x16x32_bf16(vf0, pf, acc[0][qt], 0, 0, 0);
      acc[1][qt] = __builtin_amdgcn_mfma_f32_16x16x32_bf16(vf1, pf, acc[1][qt], 0, 0, 0);
    }
  }

#pragma unroll
  for (int qt = 0; qt < 4; qt++) {
    float l = lsum[qt];
    l += __shfl_xor(l, 16);
    l += __shfl_xor(l, 32);
    lsum[qt] = 1.0f / l;
  }

  // ---- deposit O (head's 32 dims) for the 64 tokens as packed hi|lo<<16 ----
#pragma unroll
  for (int t = 0; t < 4; t++) {
    const float inv = lsum[t];
#pragma unroll
    for (int dt = 0; dt < 2; dt++) {
      floatx4 v4 = acc[dt][t];
      uint4 st;
      unsigned short hh, ll;
      split_bf(v4[0] * inv, hh, ll); st.x = (unsigned)hh | ((unsigned)ll << 16);
      split_bf(v4[1] * inv, hh, ll); st.y = (unsigned)hh | ((unsigned)ll << 16);
      split_bf(v4[2] * inv, hh, ll); st.z = (unsigned)hh | ((unsigned)ll << 16);
      split_bf(v4[3] * inv, hh, ll); st.w = (unsigned)hh | ((unsigned)ll << 16);
      *(uint4*)&Ols[t * 16 + c][h * 32 + dt * 16 + quad * 4] = st;
    }
  }

  // ---- load wo fragments: wave owns outdim tiles wave*32, wave*32+16 ----
  bf16x8 woh[2][4], wol[2][4];
#pragma unroll
  for (int mi = 0; mi < 2; mi++)
#pragma unroll
    for (int ks = 0; ks < 4; ks++) {
      const int m0 = h * 32 + mi * 16;
      woh[mi][ks] = *(const bf16x8*)(Whi + 3 * 16384 + (m0 + c) * D + ks * 32 + quad * 8);
      wol[mi][ks] = *(const bf16x8*)(Wlo + 3 * 16384 + (m0 + c) * D + ks * 32 + quad * 8);
    }

  __syncthreads();

  // ---- Phase 2: project the 64 tokens: out = O @ wo^T ----
  floatx4 oacc[2][4];
#pragma unroll
  for (int mi = 0; mi < 2; mi++)
#pragma unroll
    for (int nt = 0; nt < 4; nt++) oacc[mi][nt] = (floatx4){0.f, 0.f, 0.f, 0.f};

#pragma unroll
  for (int ks = 0; ks < 4; ks++) {
#pragma unroll
    for (int nt = 0; nt < 4; nt++) {
      const unsigned int* src = &Ols[nt * 16 + c][ks * 32 + quad * 8];
      uint4 u0 = *(const uint4*)(src);
      uint4 u1 = *(const uint4*)(src + 4);
      unsigned int bhw[4], blw[4];
      bhw[0] = (u0.x & 0xFFFFu) | (u0.y << 16);
      blw[0] = (u0.x >> 16) | (u0.y & 0xFFFF0000u);
      bhw[1] = (u0.z & 0xFFFFu) | (u0.w << 16);
      blw[1] = (u0.z >> 16) | (u0.w & 0xFFFF0000u);
      bhw[2] = (u1.x & 0xFFFFu) | (u1.y << 16);
      blw[2] = (u1.x >> 16) | (u1.y & 0xFFFF0000u);
      bhw[3] = (u1.z & 0xFFFFu) | (u1.w << 16);
      blw[3] = (u1.z >> 16) | (u1.w & 0xFFFF0000u);
      bf16x8 bh = *(bf16x8*)bhw;
      bf16x8 bl = *(bf16x8*)blw;
#pragma unroll
      for (int mi = 0; mi < 2; mi++) {
        oacc[mi][nt] = __builtin_amdgcn_mfma_f32_16x16x32_bf16(woh[mi][ks], bh, oacc[mi][nt], 0, 0, 0);
        oacc[mi][nt] = __builtin_amdgcn_mfma_f32_16x16x32_bf16(woh[mi][ks], bl, oacc[mi][nt], 0, 0, 0);
        oacc[mi][nt] = __builtin_amdgcn_mfma_f32_16x16x32_bf16(wol[mi][ks], bh, oacc[mi][nt], 0, 0, 0);
      }
    }
  }

#pragma unroll
  for (int mi = 0; mi < 2; mi++) {
    const int m0 = h * 32 + mi * 16;
#pragma unroll
    for (int nt = 0; nt < 4; nt++) {
      float4 st;
      st.x = oacc[mi][nt][0];
      st.y = oacc[mi][nt][1];
      st.z = oacc[mi][nt][2];
      st.w = oacc[mi][nt][3];
      *(float4*)(out + ((size_t)i * S + q0 + nt * 16 + c) * D + m0 + quad * 4) = st;
    }
  }
}

// ---------------------------------------------------------------------------
extern "C" void kernel_launch(void* const* d_in, const int* in_sizes, int n_in,
                              void* d_out, int out_size, void* d_ws,
                              size_t ws_size, hipStream_t stream) {
  const float* pair = (const float*)d_in[0];
  const float* ln_w = (const float*)d_in[1];
  const float* wq = (const float*)d_in[2];
  const float* wk = (const float*)d_in[3];
  const float* wv = (const float*)d_in[4];
  const float* wo = (const float*)d_in[5];
  float* out = (float*)d_out;

  const size_t NE = (size_t)NT * D;  // 8388608
  unsigned short* base = (unsigned short*)d_ws;
  unsigned short* Qb = base;
  unsigned short* Kb = base + NE;
  unsigned short* Vt = base + 2 * NE;
  unsigned short* Whi = base + 3 * NE;
  unsigned short* Wlo = base + 3 * NE + 4 * 16384;

  wsplit_kernel<<<64, 256, 0, stream>>>(wq, wk, wv, wo, Whi, Wlo);
  qkv_ln_mfma_kernel<<<NT / 64, 256, 0, stream>>>(pair, ln_w, Whi, Wlo, Qb, Kb,
                                                  Vt);
  attn_oproj_kernel<<<dim3(S, 4), 256, 0, stream>>>(Qb, Kb, Vt, Whi, Wlo, out);
}